// Round 1
// baseline (527.509 us; speedup 1.0000x reference)
//
#include <hip/hip_runtime.h>
#include <hip/hip_bf16.h>
#include <math.h>

#define D_MODEL 1024
#define HD 128
#define BATCH 4
#define SEQ 4096

typedef __bf16 bf16x8 __attribute__((ext_vector_type(8)));
typedef float f32x4 __attribute__((ext_vector_type(4)));

__device__ __forceinline__ unsigned short f2bf(float f) {
    union { float f; unsigned int u; } c; c.f = f;
    unsigned int u = c.u;
    u = (u + 0x7fffu + ((u >> 16) & 1u)) >> 16;   // RNE, no NaN inputs here
    return (unsigned short)u;
}

// ---------------------------------------------------------------------------
// Wt[n][k] = W_{q|k|v}[k][n&127], n in [0,384), bf16.  (B-operand wants n-major)
__global__ void wt_kernel(const float* __restrict__ Wq, const float* __restrict__ Wk,
                          const float* __restrict__ Wv, unsigned short* __restrict__ Wt) {
    int n = blockIdx.x;
    const float* W = (n < 128) ? Wq : (n < 256) ? Wk : Wv;
    int nl = n & 127;
    for (int k = threadIdx.x; k < D_MODEL; k += blockDim.x)
        Wt[(size_t)n * D_MODEL + k] = f2bf(W[(size_t)k * HD + nl]);
}

// ---------------------------------------------------------------------------
// QKV projection: x[16384][1024] fp32 @ Wt -> Qb,Kb row-major bf16 [16384][128],
// V written transposed: Vt[b][128][4096] bf16.
// Block: 64 rows; 4 waves each own 96 of the 384 output cols (24 acc frags).
__global__ __launch_bounds__(256)
void proj_kernel(const float* __restrict__ x, const unsigned short* __restrict__ Wt,
                 unsigned short* __restrict__ Qb, unsigned short* __restrict__ Kb,
                 unsigned short* __restrict__ Vt) {
    const int wave = threadIdx.x >> 6;
    const int lane = threadIdx.x & 63;
    const int li = lane & 15;
    const int g  = lane >> 4;
    const int rowbase = blockIdx.x * 64;
    const int nbase = wave * 96;

    f32x4 acc[4][6];
    #pragma unroll
    for (int mt = 0; mt < 4; ++mt)
        #pragma unroll
        for (int nt = 0; nt < 6; ++nt)
            acc[mt][nt] = (f32x4){0.f, 0.f, 0.f, 0.f};

    for (int k0 = 0; k0 < D_MODEL; k0 += 32) {
        const int kf = k0 + g * 8;
        bf16x8 af[4];
        #pragma unroll
        for (int mt = 0; mt < 4; ++mt) {
            const float* xp = x + (size_t)(rowbase + mt * 16 + li) * D_MODEL + kf;
            f32x4 lo = *reinterpret_cast<const f32x4*>(xp);
            f32x4 hi = *reinterpret_cast<const f32x4*>(xp + 4);
            union { unsigned short u[8]; bf16x8 v; } cv;
            #pragma unroll
            for (int j = 0; j < 4; ++j) { cv.u[j] = f2bf(lo[j]); cv.u[4 + j] = f2bf(hi[j]); }
            af[mt] = cv.v;
        }
        bf16x8 bfr[6];
        #pragma unroll
        for (int nt = 0; nt < 6; ++nt)
            bfr[nt] = *reinterpret_cast<const bf16x8*>(Wt + (size_t)(nbase + nt * 16 + li) * D_MODEL + kf);
        #pragma unroll
        for (int mt = 0; mt < 4; ++mt)
            #pragma unroll
            for (int nt = 0; nt < 6; ++nt)
                acc[mt][nt] = __builtin_amdgcn_mfma_f32_16x16x32_bf16(af[mt], bfr[nt], acc[mt][nt], 0, 0, 0);
    }

    // C/D layout: col = lane&15 (n within tile), row = (lane>>4)*4 + reg
    #pragma unroll
    for (int mt = 0; mt < 4; ++mt) {
        #pragma unroll
        for (int nt = 0; nt < 6; ++nt) {
            int n = nbase + nt * 16 + li;
            #pragma unroll
            for (int r = 0; r < 4; ++r) {
                int grow = rowbase + mt * 16 + g * 4 + r;
                unsigned short bv = f2bf(acc[mt][nt][r]);
                if (n < 128)      Qb[(size_t)grow * HD + n] = bv;
                else if (n < 256) Kb[(size_t)grow * HD + (n - 128)] = bv;
                else {
                    int b_ = grow >> 12, s_ = grow & 4095;
                    Vt[((size_t)b_ * HD + (n - 256)) * SEQ + s_] = bv;
                }
            }
        }
    }
}

// ---------------------------------------------------------------------------
// Flash causal attention. Block = 64 q rows (4 waves x 16), K-tile = 32.
__global__ __launch_bounds__(256)
void attn_kernel(const unsigned short* __restrict__ Qb, const unsigned short* __restrict__ Kb,
                 const unsigned short* __restrict__ Vt, float* __restrict__ out) {
    __shared__ unsigned short Plds[4][16][48];   // row stride 48 (96B): 16B-aligned b128 reads
    const int wave = threadIdx.x >> 6;
    const int lane = threadIdx.x & 63;
    const int li = lane & 15;
    const int g  = lane >> 4;
    const int b  = blockIdx.x >> 6;        // batch
    const int tile = blockIdx.x & 63;
    const int q0 = tile * 64;              // local q start of block
    const int qw = q0 + wave * 16;         // this wave's q start
    const size_t rowb = (size_t)b * SEQ;

    // Q fragments (A-layout: m = lane&15, k = (lane>>4)*8 + j), 4 k-steps of 32
    bf16x8 qf[4];
    #pragma unroll
    for (int kk = 0; kk < 4; ++kk)
        qf[kk] = *reinterpret_cast<const bf16x8*>(Qb + (rowb + qw + li) * HD + kk * 32 + g * 8);

    f32x4 acco[8];
    #pragma unroll
    for (int dt = 0; dt < 8; ++dt) acco[dt] = (f32x4){0.f, 0.f, 0.f, 0.f};
    float m_[4], l_[4];
    #pragma unroll
    for (int r = 0; r < 4; ++r) { m_[r] = -INFINITY; l_[r] = 0.f; }

    const float SC = 0.08838834764831845f * 1.4426950408889634f;  // 1/sqrt(128) * log2(e)
    const int nIter = q0 / 32 + 2;
    for (int it = 0; it < nIter; ++it) {
        const int j0 = it * 32;
        f32x4 accs[2] = {{0.f,0.f,0.f,0.f}, {0.f,0.f,0.f,0.f}};
        #pragma unroll
        for (int t = 0; t < 2; ++t)
            #pragma unroll
            for (int kk = 0; kk < 4; ++kk) {
                bf16x8 kf = *reinterpret_cast<const bf16x8*>(
                    Kb + (rowb + j0 + t * 16 + li) * HD + kk * 32 + g * 8);
                accs[t] = __builtin_amdgcn_mfma_f32_16x16x32_bf16(qf[kk], kf, accs[t], 0, 0, 0);
            }

        // online softmax in C layout: lane holds rows g*4+r, col = li (+16 per tile)
        float p[2][4], mx[4];
        #pragma unroll
        for (int r = 0; r < 4; ++r) {
            int qrow = qw + g * 4 + r;
            float s0 = accs[0][r] * SC; if (j0 + li > qrow)      s0 = -INFINITY;
            float s1 = accs[1][r] * SC; if (j0 + 16 + li > qrow) s1 = -INFINITY;
            p[0][r] = s0; p[1][r] = s1;
            mx[r] = fmaxf(s0, s1);
        }
        #pragma unroll
        for (int d = 1; d < 16; d <<= 1)
            #pragma unroll
            for (int r = 0; r < 4; ++r)
                mx[r] = fmaxf(mx[r], __shfl_xor(mx[r], d));
        float alpha[4], rs[4];
        #pragma unroll
        for (int r = 0; r < 4; ++r) {
            float mn = fmaxf(m_[r], mx[r]);
            alpha[r] = exp2f(m_[r] - mn);
            m_[r] = mn;
            p[0][r] = exp2f(p[0][r] - mn);
            p[1][r] = exp2f(p[1][r] - mn);
            rs[r] = p[0][r] + p[1][r];
        }
        #pragma unroll
        for (int d = 1; d < 16; d <<= 1)
            #pragma unroll
            for (int r = 0; r < 4; ++r)
                rs[r] += __shfl_xor(rs[r], d);
        #pragma unroll
        for (int r = 0; r < 4; ++r)
            l_[r] = l_[r] * alpha[r] + rs[r];

        // P: C-layout -> LDS -> A-layout (verified m120 round-trip)
        #pragma unroll
        for (int t = 0; t < 2; ++t)
            #pragma unroll
            for (int r = 0; r < 4; ++r)
                Plds[wave][g * 4 + r][t * 16 + li] = f2bf(p[t][r]);
        __syncthreads();
        bf16x8 pf = *reinterpret_cast<const bf16x8*>(&Plds[wave][li][g * 8]);

        // O = O*alpha + P@V ; Vt gives contiguous B-frags
        #pragma unroll
        for (int dt = 0; dt < 8; ++dt) {
            f32x4 a = acco[dt];
            #pragma unroll
            for (int r = 0; r < 4; ++r) a[r] *= alpha[r];
            bf16x8 vf = *reinterpret_cast<const bf16x8*>(
                Vt + ((size_t)b * HD + dt * 16 + li) * SEQ + j0 + g * 8);
            acco[dt] = __builtin_amdgcn_mfma_f32_16x16x32_bf16(pf, vf, a, 0, 0, 0);
        }
    }

    float il[4];
    #pragma unroll
    for (int r = 0; r < 4; ++r) il[r] = 1.f / l_[r];
    #pragma unroll
    for (int dt = 0; dt < 8; ++dt)
        #pragma unroll
        for (int r = 0; r < 4; ++r)
            out[(rowb + qw + g * 4 + r) * HD + dt * 16 + li] = acco[dt][r] * il[r];
}

// ---------------------------------------------------------------------------
extern "C" void kernel_launch(void* const* d_in, const int* in_sizes, int n_in,
                              void* d_out, int out_size, void* d_ws, size_t ws_size,
                              hipStream_t stream) {
    const float* x  = (const float*)d_in[0];
    const float* Wq = (const float*)d_in[1];
    const float* Wk = (const float*)d_in[2];
    const float* Wv = (const float*)d_in[3];
    float* out = (float*)d_out;

    char* ws = (char*)d_ws;
    unsigned short* Qb = (unsigned short*)(ws);                       // 4 MB
    unsigned short* Kb = (unsigned short*)(ws + ((size_t)4  << 20));  // 4 MB
    unsigned short* Vt = (unsigned short*)(ws + ((size_t)8  << 20));  // 4 MB
    unsigned short* Wt = (unsigned short*)(ws + ((size_t)12 << 20));  // 768 KB

    wt_kernel<<<dim3(384), dim3(256), 0, stream>>>(Wq, Wk, Wv, Wt);
    proj_kernel<<<dim3(256), dim3(256), 0, stream>>>(x, Wt, Qb, Kb, Vt);
    attn_kernel<<<dim3(256), dim3(256), 0, stream>>>(Qb, Kb, Vt, out);
}

// Round 2
// 281.268 us; speedup vs baseline: 1.8755x; 1.8755x over previous
//
#include <hip/hip_runtime.h>
#include <hip/hip_bf16.h>
#include <math.h>

#define D_MODEL 1024
#define HD 128
#define BATCH 4
#define SEQ 4096

typedef __bf16 bf16x8 __attribute__((ext_vector_type(8)));
typedef float f32x4 __attribute__((ext_vector_type(4)));

__device__ __forceinline__ unsigned short f2bf(float f) {
    union { float f; unsigned int u; } c; c.f = f;
    unsigned int u = c.u;
    u = (u + 0x7fffu + ((u >> 16) & 1u)) >> 16;   // RNE, no NaN inputs here
    return (unsigned short)u;
}

// ---------------------------------------------------------------------------
// Wt[n][k] = W_{q|k|v}[k][n&127], n in [0,384), bf16.  (B-operand wants n-major)
__global__ void wt_kernel(const float* __restrict__ Wq, const float* __restrict__ Wk,
                          const float* __restrict__ Wv, unsigned short* __restrict__ Wt) {
    int n = blockIdx.x;
    const float* W = (n < 128) ? Wq : (n < 256) ? Wk : Wv;
    int nl = n & 127;
    for (int k = threadIdx.x; k < D_MODEL; k += blockDim.x)
        Wt[(size_t)n * D_MODEL + k] = f2bf(W[(size_t)k * HD + nl]);
}

// ---------------------------------------------------------------------------
// QKV projection with LDS-staged x (read once, shared by 4 waves).
// Block: 64 rows x 384 cols; waves split N into 4x96 (24 acc frags each).
// Double-buffered x tile, one barrier per K-step.
__global__ __launch_bounds__(256)
void proj_kernel(const float* __restrict__ x, const unsigned short* __restrict__ Wt,
                 unsigned short* __restrict__ Qb, unsigned short* __restrict__ Kb,
                 unsigned short* __restrict__ Vt) {
    __shared__ unsigned short xs[2][64][48];   // row stride 96B (16B-aligned, min bank aliasing)
    const int tid  = threadIdx.x;
    const int wave = tid >> 6;
    const int lane = tid & 63;
    const int li = lane & 15;
    const int g  = lane >> 4;
    const int rowbase = blockIdx.x * 64;
    const int nbase = wave * 96;
    const int srow = tid >> 2;          // staging row 0..63
    const int scol = (tid & 3) * 8;     // staging col chunk

    f32x4 acc[4][6];
    #pragma unroll
    for (int mt = 0; mt < 4; ++mt)
        #pragma unroll
        for (int nt = 0; nt < 6; ++nt)
            acc[mt][nt] = (f32x4){0.f, 0.f, 0.f, 0.f};

    const float* xp = x + (size_t)(rowbase + srow) * D_MODEL + scol;
    f32x4 lo = *reinterpret_cast<const f32x4*>(xp);
    f32x4 hi = *reinterpret_cast<const f32x4*>(xp + 4);

    for (int k0 = 0; k0 < D_MODEL; k0 += 32) {
        const int buf = (k0 >> 5) & 1;
        union { unsigned short u[8]; bf16x8 v; } cv;
        #pragma unroll
        for (int j = 0; j < 4; ++j) { cv.u[j] = f2bf(lo[j]); cv.u[4 + j] = f2bf(hi[j]); }
        *reinterpret_cast<bf16x8*>(&xs[buf][srow][scol]) = cv.v;
        if (k0 + 32 < D_MODEL) {
            const float* xq = x + (size_t)(rowbase + srow) * D_MODEL + (k0 + 32) + scol;
            lo = *reinterpret_cast<const f32x4*>(xq);
            hi = *reinterpret_cast<const f32x4*>(xq + 4);
        }
        __syncthreads();
        bf16x8 af[4];
        #pragma unroll
        for (int mt = 0; mt < 4; ++mt)
            af[mt] = *reinterpret_cast<const bf16x8*>(&xs[buf][mt * 16 + li][g * 8]);
        #pragma unroll
        for (int nt = 0; nt < 6; ++nt) {
            bf16x8 bfr = *reinterpret_cast<const bf16x8*>(
                Wt + (size_t)(nbase + nt * 16 + li) * D_MODEL + k0 + g * 8);
            #pragma unroll
            for (int mt = 0; mt < 4; ++mt)
                acc[mt][nt] = __builtin_amdgcn_mfma_f32_16x16x32_bf16(af[mt], bfr, acc[mt][nt], 0, 0, 0);
        }
    }

    // C/D layout: col = lane&15, row = (lane>>4)*4 + reg
    #pragma unroll
    for (int mt = 0; mt < 4; ++mt) {
        #pragma unroll
        for (int nt = 0; nt < 6; ++nt) {
            int n = nbase + nt * 16 + li;
            #pragma unroll
            for (int r = 0; r < 4; ++r) {
                int grow = rowbase + mt * 16 + g * 4 + r;
                unsigned short bv = f2bf(acc[mt][nt][r]);
                if (n < 128)      Qb[(size_t)grow * HD + n] = bv;
                else if (n < 256) Kb[(size_t)grow * HD + (n - 128)] = bv;
                else {
                    int b_ = grow >> 12, s_ = grow & 4095;
                    Vt[((size_t)b_ * HD + (n - 256)) * SEQ + s_] = bv;
                }
            }
        }
    }
}

// ---------------------------------------------------------------------------
// Flash causal attention, split-K within block.
// Block = one 16-row q-tile; 4 waves split the valid key range into balanced
// 32-key-tile chunks; no per-iter barrier (private P slot per wave);
// one LDS merge at the end. Grid = 4 batches x 256 q-tiles = 1024 blocks.
__global__ __launch_bounds__(256)
void attn_kernel(const unsigned short* __restrict__ Qb, const unsigned short* __restrict__ Kb,
                 const unsigned short* __restrict__ Vt, float* __restrict__ out) {
    __shared__ unsigned short Plds[4][16][48];  // per-wave P round-trip
    __shared__ float Om[4][16][128];            // per-wave partial O
    __shared__ float Ml[4][2][16];              // per-wave m, l
    const int wave = threadIdx.x >> 6;
    const int lane = threadIdx.x & 63;
    const int li = lane & 15;
    const int g  = lane >> 4;
    const int b  = blockIdx.x & 3;              // batch (interleaved)
    const int qt = 255 - (blockIdx.x >> 2);     // big q-tiles dispatch first
    const int q0 = qt * 16;
    const size_t rowb = (size_t)b * SEQ;

    const int ntiles = q0 / 32 + 1;             // 32-key tiles covering [0, q0+16)
    const int ts = wave * ntiles / 4;
    const int te = (wave + 1) * ntiles / 4;

    // Q fragments (A-layout: m = lane&15, k = (lane>>4)*8 + j)
    bf16x8 qf[4];
    #pragma unroll
    for (int kk = 0; kk < 4; ++kk)
        qf[kk] = *reinterpret_cast<const bf16x8*>(Qb + (rowb + q0 + li) * HD + kk * 32 + g * 8);

    f32x4 acco[8];
    #pragma unroll
    for (int dt = 0; dt < 8; ++dt) acco[dt] = (f32x4){0.f, 0.f, 0.f, 0.f};
    float m_[4], l_[4];
    #pragma unroll
    for (int r = 0; r < 4; ++r) { m_[r] = -INFINITY; l_[r] = 0.f; }

    const float SC = 0.08838834764831845f * 1.4426950408889634f;  // 1/sqrt(128) * log2(e)
    for (int it = ts; it < te; ++it) {
        const int j0 = it * 32;
        f32x4 accs[2] = {{0.f,0.f,0.f,0.f}, {0.f,0.f,0.f,0.f}};
        #pragma unroll
        for (int t = 0; t < 2; ++t)
            #pragma unroll
            for (int kk = 0; kk < 4; ++kk) {
                bf16x8 kf = *reinterpret_cast<const bf16x8*>(
                    Kb + (rowb + j0 + t * 16 + li) * HD + kk * 32 + g * 8);
                accs[t] = __builtin_amdgcn_mfma_f32_16x16x32_bf16(qf[kk], kf, accs[t], 0, 0, 0);
            }

        // online softmax in C layout: lane holds rows g*4+r, col = li (+16 per tile)
        float p[2][4], mx[4];
        #pragma unroll
        for (int r = 0; r < 4; ++r) {
            int qrow = q0 + g * 4 + r;
            float s0 = accs[0][r] * SC; if (j0 + li > qrow)      s0 = -INFINITY;
            float s1 = accs[1][r] * SC; if (j0 + 16 + li > qrow) s1 = -INFINITY;
            p[0][r] = s0; p[1][r] = s1;
            mx[r] = fmaxf(s0, s1);
        }
        #pragma unroll
        for (int d = 1; d < 16; d <<= 1)
            #pragma unroll
            for (int r = 0; r < 4; ++r)
                mx[r] = fmaxf(mx[r], __shfl_xor(mx[r], d));
        float alpha[4], rs[4];
        #pragma unroll
        for (int r = 0; r < 4; ++r) {
            float mn = fmaxf(m_[r], mx[r]);
            alpha[r] = exp2f(m_[r] - mn);
            m_[r] = mn;
            p[0][r] = exp2f(p[0][r] - mn);
            p[1][r] = exp2f(p[1][r] - mn);
            rs[r] = p[0][r] + p[1][r];
        }
        #pragma unroll
        for (int d = 1; d < 16; d <<= 1)
            #pragma unroll
            for (int r = 0; r < 4; ++r)
                rs[r] += __shfl_xor(rs[r], d);
        #pragma unroll
        for (int r = 0; r < 4; ++r)
            l_[r] = l_[r] * alpha[r] + rs[r];

        // P: C-layout -> private LDS slot -> A-layout (in-wave ordering only)
        #pragma unroll
        for (int t = 0; t < 2; ++t)
            #pragma unroll
            for (int r = 0; r < 4; ++r)
                Plds[wave][g * 4 + r][t * 16 + li] = f2bf(p[t][r]);
        bf16x8 pf = *reinterpret_cast<const bf16x8*>(&Plds[wave][li][g * 8]);

        // O = O*alpha + P@V ; Vt gives contiguous B-frags
        #pragma unroll
        for (int dt = 0; dt < 8; ++dt) {
            f32x4 a = acco[dt];
            #pragma unroll
            for (int r = 0; r < 4; ++r) a[r] *= alpha[r];
            bf16x8 vf = *reinterpret_cast<const bf16x8*>(
                Vt + ((size_t)b * HD + dt * 16 + li) * SEQ + j0 + g * 8);
            acco[dt] = __builtin_amdgcn_mfma_f32_16x16x32_bf16(pf, vf, a, 0, 0, 0);
        }
    }

    // Publish partials
    #pragma unroll
    for (int dt = 0; dt < 8; ++dt)
        #pragma unroll
        for (int r = 0; r < 4; ++r)
            Om[wave][g * 4 + r][dt * 16 + li] = acco[dt][r];
    if (li == 0) {
        #pragma unroll
        for (int r = 0; r < 4; ++r) {
            Ml[wave][0][g * 4 + r] = m_[r];
            Ml[wave][1][g * 4 + r] = l_[r];
        }
    }
    __syncthreads();

    // Merge 4 partials: 256 threads x 8 elements of the 16x128 tile
    for (int idx = threadIdx.x; idx < 16 * 128; idx += 256) {
        const int r = idx >> 7, c = idx & 127;
        float m0 = Ml[0][0][r], m1 = Ml[1][0][r], m2 = Ml[2][0][r], m3 = Ml[3][0][r];
        float M = fmaxf(fmaxf(m0, m1), fmaxf(m2, m3));
        float w0 = exp2f(m0 - M), w1 = exp2f(m1 - M), w2 = exp2f(m2 - M), w3 = exp2f(m3 - M);
        float L = Ml[0][1][r] * w0 + Ml[1][1][r] * w1 + Ml[2][1][r] * w2 + Ml[3][1][r] * w3;
        float o = Om[0][r][c] * w0 + Om[1][r][c] * w1 + Om[2][r][c] * w2 + Om[3][r][c] * w3;
        out[(rowb + q0 + r) * HD + c] = o / L;
    }
}

// ---------------------------------------------------------------------------
extern "C" void kernel_launch(void* const* d_in, const int* in_sizes, int n_in,
                              void* d_out, int out_size, void* d_ws, size_t ws_size,
                              hipStream_t stream) {
    const float* x  = (const float*)d_in[0];
    const float* Wq = (const float*)d_in[1];
    const float* Wk = (const float*)d_in[2];
    const float* Wv = (const float*)d_in[3];
    float* out = (float*)d_out;

    char* ws = (char*)d_ws;
    unsigned short* Qb = (unsigned short*)(ws);                       // 4 MB
    unsigned short* Kb = (unsigned short*)(ws + ((size_t)4  << 20));  // 4 MB
    unsigned short* Vt = (unsigned short*)(ws + ((size_t)8  << 20));  // 4 MB
    unsigned short* Wt = (unsigned short*)(ws + ((size_t)12 << 20));  // 768 KB

    wt_kernel<<<dim3(384), dim3(256), 0, stream>>>(Wq, Wk, Wv, Wt);
    proj_kernel<<<dim3(256), dim3(256), 0, stream>>>(x, Wt, Qb, Kb, Vt);
    attn_kernel<<<dim3(1024), dim3(256), 0, stream>>>(Qb, Kb, Vt, out);
}